// Round 7
// baseline (100.989 us; speedup 1.0000x reference)
//
#include <hip/hip_runtime.h>

// Problem constants (fixed by setup_inputs)
constexpr int H_OUT = 256;
constexpr int D     = 256;   // Wl * KC

typedef __bf16 bf16x8 __attribute__((ext_vector_type(8)));
typedef float  f32x16 __attribute__((ext_vector_type(16)));

// fp32 -> bf16, round-to-nearest-even
__device__ __forceinline__ ushort f2bf(float f) {
    uint u = __float_as_uint(f);
    u = (u + 0x7FFFu + ((u >> 16) & 1u)) >> 16;
    return (ushort)u;
}
__device__ __forceinline__ uint pack2(float a, float b) {
    return (uint)f2bf(a) | ((uint)f2bf(b) << 16);
}

// async global(16B/lane) -> LDS(base + lane*16), lane-linear dest
__device__ __forceinline__ void gll16(const ushort* g, void* lds) {
    __builtin_amdgcn_global_load_lds(
        (const __attribute__((address_space(1))) uint*)g,
        (__attribute__((address_space(3))) uint*)lds, 16, 0, 0);
}

// ---- pre-kernel: x fp32 -> bf16 (one-time cvt; kills 8x-redundant cvt) ----
__global__ __launch_bounds__(256) void cvt_x_bf16(
    const float* __restrict__ x, ushort* __restrict__ xb)
{
    const int t = blockIdx.x * 256 + threadIdx.x;   // 8 elems / thread
    const float4 a = ((const float4*)x)[2 * t];
    const float4 b = ((const float4*)x)[2 * t + 1];
    uint4 o;
    o.x = pack2(a.x, a.y); o.y = pack2(a.z, a.w);
    o.z = pack2(b.x, b.y); o.w = pack2(b.z, b.w);
    ((uint4*)xb)[t] = o;
}

// Block = (h, batch-half), 4 batch-tiles of 64 rows.
// W[h] fragments live in registers (coalesced fp32 load, cvt once in prologue);
// x tiles double-buffered in LDS via global_load_lds with source-side XOR
// pre-swizzle (rule #21: linear dest + inverse-swz source + swz read).
__global__ __launch_bounds__(256, 2) void sparse_linear_mfma4(
    const ushort* __restrict__ xb,    // [512, 128, 64] bf16 (ws)
    const int*   __restrict__ mask,   // [256, 4]
    const float* __restrict__ W,      // [256, 64, 256] fp32
    const float* __restrict__ bias,   // [256, 64]
    float*       __restrict__ out)    // [512, 256, 64] fp32
{
    const int bx   = blockIdx.x;
    const int h    = bx & 255;        // bx%8 == h%8 -> halves share W on one XCD
    const int half = bx >> 8;
    const int tid  = threadIdx.x;
    const int lane = tid & 63, wid = tid >> 6;
    const int wr   = (wid >> 1) * 32;   // batch-row quarter within tile
    const int wc   = (wid & 1) * 32;    // out-col half
    const int rowl = lane & 31, hi = lane >> 5;

    // 64 rows x 32 slots of 16B bf16x8; LDS[rr][j] holds gathered chunk j^(rr&15)
    __shared__ float4 Xls[2][64 * 32];  // 2 x 32 KB

    // ---- B fragments (regs, once): lane = col wc+rowl, k = ks*16 + hi*8 .. +7.
    // Lane pairs (l, l+32) cover one 64B line -> fully coalesced fp32 reads.
    bf16x8 bfrag[16];
    {
        const float* wp = W + ((size_t)(h * 64 + wc + rowl)) * D + hi * 8;
        #pragma unroll
        for (int ks = 0; ks < 16; ++ks) {
            const float4 lo = *(const float4*)(wp + ks * 16);
            const float4 h4 = *(const float4*)(wp + ks * 16 + 4);
            uint4 o;
            o.x = pack2(lo.x, lo.y); o.y = pack2(lo.z, lo.w);
            o.z = pack2(h4.x, h4.y); o.w = pack2(h4.z, h4.w);
            bfrag[ks] = __builtin_bit_cast(bf16x8, o);
        }
    }
    const float bv = bias[h * 64 + wc + rowl];

    const int m0 = mask[h * 4 + 0], m1 = mask[h * 4 + 1];
    const int m2 = mask[h * 4 + 2], m3 = mask[h * 4 + 3];

    // ---- staging source addrs: wave stages rows 16*wid..+15 as 8 issues x 2 rows.
    // Lane l -> row rr = 16*wid + 2*i + (l>>5), linear slot j = l&31.
    // Source carries the inverse swizzle: chunk c = j ^ (rr&15), d = c*8..c*8+7,
    // i.e. x row mask[c>>3], 16B sub-chunk c&7.
    const ushort* gsrc[8];
    #pragma unroll
    for (int i = 0; i < 8; ++i) {
        const int rr = 16 * wid + 2 * i + hi;
        const int c  = (lane & 31) ^ (rr & 15);
        const int mrow = (c & 16) ? ((c & 8) ? m3 : m2) : ((c & 8) ? m1 : m0);
        gsrc[i] = xb + ((size_t)(half * 256 + rr) * 128 + mrow) * 64 + (c & 7) * 8;
    }

    // prologue: stage tile 0 (linear dest; __syncthreads drains vmcnt -> published)
    #pragma unroll
    for (int i = 0; i < 8; ++i)
        gll16(gsrc[i], &Xls[0][(16 * wid + 2 * i) * 32]);
    __syncthreads();

    const int ra   = wr + rowl;
    const int xorv = ra & 15;

    #pragma unroll
    for (int bt = 0; bt < 4; ++bt) {
        // issue next tile's loads into the other buffer; fly under compute+stores
        if (bt < 3) {
            #pragma unroll
            for (int i = 0; i < 8; ++i) {
                gsrc[i] += 64 * 128 * 64;   // +64 batch rows
                gll16(gsrc[i], &Xls[(bt + 1) & 1][(16 * wid + 2 * i) * 32]);
            }
        }

        // compute: wave's 32x32 quadrant, 1 ds_read per MFMA, 2 acc chains
        const float4* xbuf = Xls[bt & 1];
        f32x16 acc0 = {}, acc1 = {};
        #pragma unroll
        for (int ks = 0; ks < 16; ks += 2) {
            bf16x8 a0 = __builtin_bit_cast(bf16x8, xbuf[ra * 32 + ((ks * 2 + hi) ^ xorv)]);
            bf16x8 a1 = __builtin_bit_cast(bf16x8, xbuf[ra * 32 + (((ks + 1) * 2 + hi) ^ xorv)]);
            acc0 = __builtin_amdgcn_mfma_f32_32x32x16_bf16(a0, bfrag[ks],     acc0, 0, 0, 0);
            acc1 = __builtin_amdgcn_mfma_f32_32x32x16_bf16(a1, bfrag[ks + 1], acc1, 0, 0, 0);
        }

        // epilogue: C/D layout col=lane&31, row=(reg&3)+8*(reg>>2)+4*hi
        #pragma unroll
        for (int reg = 0; reg < 16; ++reg) {
            const int rl = (reg & 3) + 8 * (reg >> 2) + 4 * hi;
            const size_t b = (size_t)half * 256 + bt * 64 + wr + rl;
            out[(b * H_OUT + h) * 64 + wc + rowl] = acc0[reg] + acc1[reg] + bv;
        }

        // one barrier/tile: drains this wave's glls (vmcnt(0) in barrier) + syncs.
        // WAR safe: glls target the buffer whose reads finished BEFORE the
        // previous barrier.
        if (bt < 3) __syncthreads();
    }
}

extern "C" void kernel_launch(void* const* d_in, const int* in_sizes, int n_in,
                              void* d_out, int out_size, void* d_ws, size_t ws_size,
                              hipStream_t stream) {
    const float* x    = (const float*)d_in[0];
    const int*   mask = (const int*)d_in[1];
    const float* W    = (const float*)d_in[2];
    const float* bias = (const float*)d_in[3];
    float*  out = (float*)d_out;
    ushort* xb  = (ushort*)d_ws;   // 512*128*64 bf16 = 8.4 MB

    cvt_x_bf16<<<dim3(2048), dim3(256), 0, stream>>>(x, xb);          // 4,194,304 elems
    sparse_linear_mfma4<<<dim3(512), dim3(256), 0, stream>>>(xb, mask, W, bias, out);
}

// Round 9
// 98.501 us; speedup vs baseline: 1.0252x; 1.0252x over previous
//
#include <hip/hip_runtime.h>

// Problem constants (fixed by setup_inputs)
constexpr int H_OUT = 256;
constexpr int D     = 256;   // W_in * K_gather

typedef __bf16 bf16x8 __attribute__((ext_vector_type(8)));
typedef float  f32x16 __attribute__((ext_vector_type(16)));

// fp32 -> bf16, round-to-nearest-even
__device__ __forceinline__ ushort f2bf(float f) {
    uint u = __float_as_uint(f);
    u = (u + 0x7FFFu + ((u >> 16) & 1u)) >> 16;
    return (ushort)u;
}
__device__ __forceinline__ uint2 pack4(float4 v) {
    uint2 r;
    r.x = (uint)f2bf(v.x) | ((uint)f2bf(v.y) << 16);
    r.y = (uint)f2bf(v.z) | ((uint)f2bf(v.w) << 16);
    return r;
}

// Block = (h, batch-half), 4 batch-tiles of 64 rows.
// KEY CHANGE vs r5/r6/r7: bx -> (h, half) mapping puts BOTH halves of an h on
// the SAME XCD (bx%8 == h%8), 8 blocks apart in dispatch order. The second
// half's W[h] read (64 KB) then L2-hits (per-XCD live W set = 32 x 64 KB =
// 2 MB < 4 MB L2) => W read from HBM ONCE: 134 -> 67 MB, the dominant traffic.
// W bf16 in LDS (32 KB) + x single-buffer (32 KB) = 64 KB => 2 blocks/CU;
// VGPR ~110 <= 128 cap => no spill at __launch_bounds__(256,2).
__global__ __launch_bounds__(256, 2) void sparse_linear_v5(
    const float* __restrict__ x,      // [512, 128, 64] fp32
    const int*   __restrict__ mask,   // [256, 4]
    const float* __restrict__ W,      // [256, 64, 256] fp32
    const float* __restrict__ bias,   // [256, 64]
    float*       __restrict__ out)    // [512, 256, 64] fp32
{
    const int bx   = blockIdx.x;
    const int xcd  = bx & 7;
    const int seq  = bx >> 3;              // within-XCD sequence 0..63
    const int h    = (seq >> 1) * 8 + xcd; // halves of h: bx and bx+8 (same XCD)
    const int half = seq & 1;
    const int tid  = threadIdx.x;
    const int lane = tid & 63, wid = tid >> 6;
    const int wr   = (wid >> 1) * 32;   // batch-row half of 64-row tile
    const int wc   = (wid & 1) * 32;    // out-col half
    const int rowl = lane & 31, hi = lane >> 5;

    // 64 rows x 32 slots of 16B (8 bf16), XOR-swizzled: slot ^= (row & 15)
    __shared__ float4 Wls[64 * 32];   // 32 KB, resident whole kernel
    __shared__ float4 Xls[64 * 32];   // 32 KB, restaged per batch-tile

    // ---- staging roles ----
    const int xrr = tid >> 4;   // x: row-within-16-group; 16 lanes per 256B row
    const int xc  = tid & 15;   // x: float4 col within row
    int mq[4];
    #pragma unroll
    for (int q = 0; q < 4; ++q) mq[q] = mask[h * 4 + q];

    // 1) issue x tile-0 loads FIRST (latency hides under W staging)
    float4 xr[16];
    #pragma unroll
    for (int p = 0; p < 16; ++p) {
        const int q  = p >> 2;
        const int rr = (p & 3) * 16 + xrr;
        xr[p] = *(const float4*)(x + ((size_t)(half * 256 + rr) * 128 + mq[q]) * 64 + xc * 4);
    }

    // 2) stage W[h] -> bf16 LDS, fully coalesced (per instr: wave reads one
    //    row's 64 float4 = 1 KB contiguous). Two passes of 8 keep regs low.
    {
        const int wrow = tid >> 6;            // wave id
        const int c    = tid & 63;            // float4 col (k = 4c)
        const float4* wsrc = (const float4*)(W + (size_t)h * 64 * D);
        #pragma unroll
        for (int pp = 0; pp < 2; ++pp) {
            float4 v[8];
            #pragma unroll
            for (int p = 0; p < 8; ++p)
                v[p] = wsrc[(size_t)((pp * 8 + p) * 4 + wrow) * 64 + c];
            #pragma unroll
            for (int p = 0; p < 8; ++p) {
                const int R = (pp * 8 + p) * 4 + wrow;
                const int s = c >> 1, hf = c & 1;
                *((uint2*)&Wls[R * 32 + (s ^ (R & 15))] + hf) = pack4(v[p]);
            }
        }
    }

    // 3) publish x tile 0
    #pragma unroll
    for (int p = 0; p < 16; ++p) {
        const int q  = p >> 2;
        const int rr = (p & 3) * 16 + xrr;
        const int s  = q * 8 + (xc >> 1), hf = xc & 1;
        *((uint2*)&Xls[rr * 32 + (s ^ (rr & 15))] + hf) = pack4(xr[p]);
    }
    __syncthreads();

    const int   ra = wr + rowl;
    const int   rb = wc + rowl;
    const float bv = bias[h * 64 + wc + rowl];

    #pragma unroll
    for (int bt = 0; bt < 4; ++bt) {
        // T14: issue next tile's coalesced loads before compute
        if (bt < 3) {
            #pragma unroll
            for (int p = 0; p < 16; ++p) {
                const int q  = p >> 2;
                const int rr = (p & 3) * 16 + xrr;
                xr[p] = *(const float4*)(x + ((size_t)(half * 256 + (bt + 1) * 64 + rr) * 128
                                              + mq[q]) * 64 + xc * 4);
            }
        }

        // compute this 64x64 tile: wave does 32x32, 2 acc chains for ILP
        f32x16 acc0 = {}, acc1 = {};
        #pragma unroll
        for (int ks = 0; ks < 16; ks += 2) {
            bf16x8 a0 = __builtin_bit_cast(bf16x8, Xls[ra * 32 + ((ks * 2 + hi) ^ (ra & 15))]);
            bf16x8 b0 = __builtin_bit_cast(bf16x8, Wls[rb * 32 + ((ks * 2 + hi) ^ (rb & 15))]);
            bf16x8 a1 = __builtin_bit_cast(bf16x8, Xls[ra * 32 + (((ks + 1) * 2 + hi) ^ (ra & 15))]);
            bf16x8 b1 = __builtin_bit_cast(bf16x8, Wls[rb * 32 + (((ks + 1) * 2 + hi) ^ (rb & 15))]);
            acc0 = __builtin_amdgcn_mfma_f32_32x32x16_bf16(a0, b0, acc0, 0, 0, 0);
            acc1 = __builtin_amdgcn_mfma_f32_32x32x16_bf16(a1, b1, acc1, 0, 0, 0);
        }

        // epilogue: C/D layout col=lane&31, row=(reg&3)+8*(reg>>2)+4*hi
        #pragma unroll
        for (int reg = 0; reg < 16; ++reg) {
            const int rl = (reg & 3) + 8 * (reg >> 2) + 4 * hi;
            const size_t b = (size_t)half * 256 + bt * 64 + wr + rl;
            out[(b * H_OUT + h) * 64 + wc + rowl] = acc0[reg] + acc1[reg] + bv;
        }

        // single-buffer x: drain reads, write next tile, publish
        if (bt < 3) {
            __syncthreads();
            #pragma unroll
            for (int p = 0; p < 16; ++p) {
                const int q  = p >> 2;
                const int rr = (p & 3) * 16 + xrr;
                const int s  = q * 8 + (xc >> 1), hf = xc & 1;
                *((uint2*)&Xls[rr * 32 + (s ^ (rr & 15))] + hf) = pack4(xr[p]);
            }
            __syncthreads();
        }
    }
}

extern "C" void kernel_launch(void* const* d_in, const int* in_sizes, int n_in,
                              void* d_out, int out_size, void* d_ws, size_t ws_size,
                              hipStream_t stream) {
    const float* x    = (const float*)d_in[0];
    const int*   mask = (const int*)d_in[1];
    const float* W    = (const float*)d_in[2];
    const float* bias = (const float*)d_in[3];
    float* out = (float*)d_out;

    dim3 grid(512);   // (h, half) via XCD-aware mapping; 2 blocks/CU
    dim3 block(256);
    sparse_linear_v5<<<grid, block, 0, stream>>>(x, mask, W, bias, out);
}